// Round 2
// baseline (481.842 us; speedup 1.0000x reference)
//
#include <hip/hip_runtime.h>

// CRF NLL forward loss. B=256, T=2048, K2=52 (50 labels + START=50 + STOP=51).
// BIDIRECTIONAL linear-domain recurrence: score = s^T D_L M ... D_1 M v0 split at
// h = L/2. Wave 0 (forward):  v <- E_t * (M v),      t = 0..h-1
// Wave 1 (backward): u <- M^T (E_t * u),             t = L-1..h
// score = ln2*(C_f + C_b + log2(sum u.*v)).
//
// R8 change: R7's VGPR_Count=52 proved the allocator demoted the 52 resident M
// values (remat/spill inside the loop) because the matvec macro held 13 live
// float4 broadcast temps (52 regs) at once. Fix: (a) stream the LDS broadcast
// through an 8-deep register rotation (peak 32 temp regs, still covers ~120cyc
// LDS latency); (b) PIN_ALL *inside* the loop so the M values are loop-carried
// asm operands the allocator must keep in VGPRs.
// Renorm by a fixed always-positive component every 4 steps (growth < 2^84).

#define B_    256
#define T_    2048
#define K2_   52
#define LOG2E_ 1.4426950408889634f
#define LN2_   0.6931471805599453f

__device__ __forceinline__ int imin(int a, int b) { return a < b ? a : b; }
__device__ __forceinline__ int imax(int a, int b) { return a > b ? a : b; }

#define FORALL52(F) \
  F(0) F(1) F(2) F(3) F(4) F(5) F(6) F(7) F(8) F(9) F(10) F(11) F(12) F(13) \
  F(14) F(15) F(16) F(17) F(18) F(19) F(20) F(21) F(22) F(23) F(24) F(25) \
  F(26) F(27) F(28) F(29) F(30) F(31) F(32) F(33) F(34) F(35) F(36) F(37) \
  F(38) F(39) F(40) F(41) F(42) F(43) F(44) F(45) F(46) F(47) F(48) F(49) \
  F(50) F(51)

// M_i = matrix entry for input component i. Forward: row n of M. Backward: col n.
#define DECLM_F(i) float M_##i = __builtin_amdgcn_exp2f(tr[n * K2_ + i] * LOG2E_);
#define DECLM_B(i) float M_##i = __builtin_amdgcn_exp2f(tr[i * K2_ + n] * LOG2E_);

#define PIN(a,b,c,d,e,f,g,h,i,j,k,l,m) \
  asm volatile("" : "+v"(M_##a), "+v"(M_##b), "+v"(M_##c), "+v"(M_##d), \
                    "+v"(M_##e), "+v"(M_##f), "+v"(M_##g), "+v"(M_##h), \
                    "+v"(M_##i), "+v"(M_##j), "+v"(M_##k), "+v"(M_##l), \
                    "+v"(M_##m));
#define PIN_ALL \
  PIN( 0, 1, 2, 3, 4, 5, 6, 7, 8, 9,10,11,12) \
  PIN(13,14,15,16,17,18,19,20,21,22,23,24,25) \
  PIN(26,27,28,29,30,31,32,33,34,35,36,37,38) \
  PIN(39,40,41,42,43,44,45,46,47,48,49,50,51)

#define ACCQ(Q, i0,i1,i2,i3) \
  _a0 = fmaf(M_##i0, (Q).x, _a0); \
  _a1 = fmaf(M_##i1, (Q).y, _a1); \
  _a2 = fmaf(M_##i2, (Q).z, _a2); \
  _a3 = fmaf(M_##i3, (Q).w, _a3);

// Forward matvec: 8-deep streamed rotation; renorm group (48..51, .z) first.
#define MATVEC_F(OUTY, RENORMV) \
    const float4* _g4 = (const float4*)sh; \
    float4 _r0 = _g4[12], _r1 = _g4[0], _r2 = _g4[1], _r3 = _g4[2]; \
    float4 _r4 = _g4[3],  _r5 = _g4[4], _r6 = _g4[5], _r7 = _g4[6]; \
    float RENORMV = _r0.z; (void)RENORMV; \
    float _a0 = 0.0f, _a1 = 0.0f, _a2 = 0.0f, _a3 = 0.0f; \
    ACCQ(_r0,48,49,50,51)  _r0 = _g4[7]; \
    ACCQ(_r1, 0, 1, 2, 3)  _r1 = _g4[8]; \
    ACCQ(_r2, 4, 5, 6, 7)  _r2 = _g4[9]; \
    ACCQ(_r3, 8, 9,10,11)  _r3 = _g4[10]; \
    ACCQ(_r4,12,13,14,15)  _r4 = _g4[11]; \
    ACCQ(_r5,16,17,18,19) \
    ACCQ(_r6,20,21,22,23) \
    ACCQ(_r7,24,25,26,27) \
    ACCQ(_r0,28,29,30,31) \
    ACCQ(_r1,32,33,34,35) \
    ACCQ(_r2,36,37,38,39) \
    ACCQ(_r3,40,41,42,43) \
    ACCQ(_r4,44,45,46,47) \
    float OUTY = (_a0 + _a1) + (_a2 + _a3);

// Backward matvec: renorm group (0..3, .x) first.
#define MATVEC_B(OUTY, RENORMV) \
    const float4* _g4 = (const float4*)sh; \
    float4 _r0 = _g4[0], _r1 = _g4[1], _r2 = _g4[2], _r3 = _g4[3]; \
    float4 _r4 = _g4[4], _r5 = _g4[5], _r6 = _g4[6], _r7 = _g4[7]; \
    float RENORMV = _r0.x; (void)RENORMV; \
    float _a0 = 0.0f, _a1 = 0.0f, _a2 = 0.0f, _a3 = 0.0f; \
    ACCQ(_r0, 0, 1, 2, 3)  _r0 = _g4[8]; \
    ACCQ(_r1, 4, 5, 6, 7)  _r1 = _g4[9]; \
    ACCQ(_r2, 8, 9,10,11)  _r2 = _g4[10]; \
    ACCQ(_r3,12,13,14,15)  _r3 = _g4[11]; \
    ACCQ(_r4,16,17,18,19)  _r4 = _g4[12]; \
    ACCQ(_r5,20,21,22,23) \
    ACCQ(_r6,24,25,26,27) \
    ACCQ(_r7,28,29,30,31) \
    ACCQ(_r0,32,33,34,35) \
    ACCQ(_r1,36,37,38,39) \
    ACCQ(_r2,40,41,42,43) \
    ACCQ(_r3,44,45,46,47) \
    ACCQ(_r4,48,49,50,51) \
    float OUTY = (_a0 + _a1) + (_a2 + _a3);

// ---- forward steps: v' = E_t * (M v); LDS holds v. Renorm comp 50 (>0). ----
#define FSTEP_R(EV, NEWIDX) do {                                \
    float _ne  = emb[(size_t)(NEWIDX) * K2_ + n];               \
    MATVEC_F(_y, _m)                                            \
    float _inv = __builtin_amdgcn_rcpf(_m);                     \
    C += __builtin_amdgcn_logf(_m);                             \
    float _E = __builtin_amdgcn_exp2f((EV) * LOG2E_);           \
    vv = _y * (_inv * _E);                                      \
    sh[lane] = vv;                                              \
    EV = _ne;                                                   \
  } while (0)
#define FSTEP_N(EV, NEWIDX) do {                                \
    float _ne  = emb[(size_t)(NEWIDX) * K2_ + n];               \
    MATVEC_F(_y, _mu)                                           \
    float _E = __builtin_amdgcn_exp2f((EV) * LOG2E_);           \
    vv = _y * _E;                                               \
    sh[lane] = vv;                                              \
    EV = _ne;                                                   \
  } while (0)

// ---- backward steps: LDS holds w = E .* u; step reads w, u' = M^T w, then
//      writes w' = u' * E_next (EV holds the NEXT step's emission). ----
#define BSTEP_R(EV, NEWIDX) do {                                \
    float _ne  = emb[(size_t)(NEWIDX) * K2_ + n];               \
    MATVEC_B(_y, _m)                                            \
    float _inv = __builtin_amdgcn_rcpf(_m);                     \
    C += __builtin_amdgcn_logf(_m);                             \
    vv = _y * _inv;                                             \
    float _E = __builtin_amdgcn_exp2f((EV) * LOG2E_);           \
    sh[lane] = vv * _E;                                         \
    EV = _ne;                                                   \
  } while (0)
#define BSTEP_N(EV, NEWIDX) do {                                \
    float _ne  = emb[(size_t)(NEWIDX) * K2_ + n];               \
    MATVEC_B(_y, _mu)                                           \
    vv = _y;                                                    \
    float _E = __builtin_amdgcn_exp2f((EV) * LOG2E_);           \
    sh[lane] = vv * _E;                                         \
    EV = _ne;                                                   \
  } while (0)

__launch_bounds__(128, 1)
__global__ void crf_fwd_kernel(const float* __restrict__ em,
                               const float* __restrict__ tr,
                               const int*  __restrict__ len,
                               const int*  __restrict__ lab,
                               float* __restrict__ per_b)
{
  const int b    = blockIdx.x;
  const int tid  = threadIdx.x;                      // 128 = 2 waves
  const int wave = tid >> 6;
  const int lane = tid & 63;
  const int n    = (lane < K2_) ? lane : (K2_ - 1);  // lanes 52..63 mirror lane 51
  const int L    = len[b];
  const int h    = L >> 1;                           // forward steps; backward L-h
  const float* emb = em + (size_t)b * (T_ * K2_);

  __shared__ __align__(16) float sV[2][64];   // per-wave state vector (broadcast)
  __shared__ float sCb[1];                    // backward wave's log-offset
  __shared__ float sG[2];                     // per-wave gold partials

  float* sh = sV[wave];
  float vv, C = 0.0f;

  if (wave == 0) {
    // ---------------- forward half: h steps, rows 0..h-1 ----------------
    FORALL52(DECLM_F)
    PIN_ALL
    vv = (lane == 50) ? 1.0f : 0.0f;
    sh[lane] = vv;
    float e0 = emb[0 * K2_ + n];
    float e1 = emb[1 * K2_ + n];
    float e2 = emb[2 * K2_ + n];
    float e3 = emb[3 * K2_ + n];
    int t = 0;
    for (; t + 4 <= h; t += 4) {
      PIN_ALL                                  // force M residency across the loop
      int i4 = imin(t + 4, T_ - 1), i5 = imin(t + 5, T_ - 1);
      int i6 = imin(t + 6, T_ - 1), i7 = imin(t + 7, T_ - 1);
      FSTEP_R(e0, i4);
      FSTEP_N(e1, i5);
      FSTEP_N(e2, i6);
      FSTEP_N(e3, i7);
    }
    int rem = h - t;
    if (rem > 0) FSTEP_R(e0, T_ - 1);
    if (rem > 1) FSTEP_N(e1, T_ - 1);
    if (rem > 2) FSTEP_N(e2, T_ - 1);
  } else {
    // ---------------- backward half: cnt = L-h steps, rows L-1 down to h ----
    FORALL52(DECLM_B)
    PIN_ALL
    vv = __builtin_amdgcn_exp2f(tr[(K2_ - 1) * K2_ + n] * LOG2E_);  // u_0 = s
    int cnt = L - h;
    float e0 = emb[(size_t)(L - 1) * K2_ + n];            // E for step 1 (pre-write)
    float eA = emb[(size_t)imax(L - 2, 0) * K2_ + n];     // next-E for step 1
    float eB = emb[(size_t)imax(L - 3, 0) * K2_ + n];     // next-E for step 2
    float eC = emb[(size_t)imax(L - 4, 0) * K2_ + n];     // next-E for step 3
    float eD = emb[(size_t)imax(L - 5, 0) * K2_ + n];     // next-E for step 4
    sh[lane] = vv * __builtin_amdgcn_exp2f(e0 * LOG2E_);  // w_0 = E_{L-1} .* u_0
    int s = 0;
    for (; s + 4 <= cnt; s += 4) {
      PIN_ALL                                  // force M residency across the loop
      int j4 = imax(L - 6 - s, 0), j5 = imax(L - 7 - s, 0);
      int j6 = imax(L - 8 - s, 0), j7 = imax(L - 9 - s, 0);
      BSTEP_R(eA, j4);
      BSTEP_N(eB, j5);
      BSTEP_N(eC, j6);
      BSTEP_N(eD, j7);
    }
    int rem = cnt - s;
    if (rem > 0) BSTEP_R(eA, 0);
    if (rem > 1) BSTEP_N(eB, 0);
    if (rem > 2) BSTEP_N(eC, 0);

    sh[lane] = vv;              // publish final u (overwrites w buffer)
    if (lane == 0) sCb[0] = C;
  }

  // ---- gold score (both waves, stride 128) ----
  float gold = 0.0f;
  const int* labb = lab + b * T_;
  for (int tt = tid; tt < L; tt += 128) {
    int l1 = labb[tt];
    int l0 = (tt == 0) ? 50 : labb[tt - 1];
    gold += emb[(size_t)tt * K2_ + l1] + tr[l1 * K2_ + l0];
  }
  if (tid == 0) gold += tr[(K2_ - 1) * K2_ + labb[L - 1]];  // STOP <- last label
#pragma unroll
  for (int off = 32; off >= 1; off >>= 1)
    gold += __shfl_xor(gold, off, 64);
  if (lane == 0) sG[wave] = gold;

  __syncthreads();

  if (wave == 0) {
    // dot(u, v) + combine log-offsets
    float x = (lane < K2_) ? vv * sV[1][lane] : 0.0f;
#pragma unroll
    for (int off = 32; off >= 1; off >>= 1)
      x += __shfl_xor(x, off, 64);
    float fwd = (C + sCb[0] + __builtin_amdgcn_logf(x)) * LN2_;
    if (lane == 0) per_b[b] = fwd - (sG[0] + sG[1]);
  }
}

__global__ void reduce_mean_kernel(const float* __restrict__ per_b,
                                   float* __restrict__ out)
{
  const int tid = threadIdx.x;  // 256
  float v = per_b[tid];
#pragma unroll
  for (int off = 32; off >= 1; off >>= 1) v += __shfl_xor(v, off, 64);
  __shared__ float s[4];
  if ((tid & 63) == 0) s[tid >> 6] = v;
  __syncthreads();
  if (tid == 0) out[0] = ((s[0] + s[1]) + (s[2] + s[3])) * (1.0f / (float)B_);
}

extern "C" void kernel_launch(void* const* d_in, const int* in_sizes, int n_in,
                              void* d_out, int out_size, void* d_ws, size_t ws_size,
                              hipStream_t stream) {
  const float* em  = (const float*)d_in[0];   // [B,T,K2] f32
  const float* tr  = (const float*)d_in[1];   // [K2,K2]  f32
  const int*   len = (const int*)d_in[2];     // [B] i32
  const int*   lab = (const int*)d_in[3];     // [B,T] i32
  float* out = (float*)d_out;
  float* ws  = (float*)d_ws;                  // 256 floats of per-batch scores

  crf_fwd_kernel<<<B_, 128, 0, stream>>>(em, tr, len, lab, ws);
  reduce_mean_kernel<<<1, 256, 0, stream>>>(ws, out);
}

// Round 3
// 395.362 us; speedup vs baseline: 1.2187x; 1.2187x over previous
//
#include <hip/hip_runtime.h>

// CRF NLL forward loss. B=256, T=2048, K2=52 (50 labels + START=50 + STOP=51).
// BIDIRECTIONAL linear-domain recurrence: score = s^T D_L M ... D_1 M v0 split at
// h = L/2. Wave 0 (forward):  v <- E_t * (M v),      t = 0..h-1
// Wave 1 (backward): u <- M^T (E_t * u),             t = L-1..h
// score = ln2*(C_f + C_b + log2(sum u.*v)).
//
// R9 change: R7/R8 counters (VGPR=52/72, zero scratch traffic) showed regalloc
// REMATERIALIZES M_i = exp2(tr[..]*c) inside the loop (const-load+mul+exp2 is
// trivially remat'able) instead of keeping 52 values resident — that per-step
// recompute was the ~650cyc/step cost. Fix: define each M_i INSIDE an opaque
// inline asm (v_exp_f32 + s_nop 1 for the trans->VALU wait state). LLVM never
// remats an INLINEASM def, and spilling 52 per-iteration-hot values to scratch
// loses the allocator's cost model -> M stays resident. Loop body reverts to
// R7's 13-upfront float4 broadcast (schedule was fine; operands weren't).
// Renorm by a fixed always-positive component every 4 steps (growth < 2^84).

#define B_    256
#define T_    2048
#define K2_   52
#define LOG2E_ 1.4426950408889634f
#define LN2_   0.6931471805599453f

__device__ __forceinline__ int imin(int a, int b) { return a < b ? a : b; }
__device__ __forceinline__ int imax(int a, int b) { return a > b ? a : b; }

#define FORALL52(F) \
  F(0) F(1) F(2) F(3) F(4) F(5) F(6) F(7) F(8) F(9) F(10) F(11) F(12) F(13) \
  F(14) F(15) F(16) F(17) F(18) F(19) F(20) F(21) F(22) F(23) F(24) F(25) \
  F(26) F(27) F(28) F(29) F(30) F(31) F(32) F(33) F(34) F(35) F(36) F(37) \
  F(38) F(39) F(40) F(41) F(42) F(43) F(44) F(45) F(46) F(47) F(48) F(49) \
  F(50) F(51)

// M_i = exp(tr entry) for input component i, defined by an OPAQUE asm so the
// register allocator cannot rematerialize it inside the loop (INLINEASM defs
// are never remat candidates). v_exp_f32 computes 2^x; input pre-scaled by
// log2(e). s_nop 1 covers the trans-op -> VALU read wait state, which the
// hazard recognizer cannot insert across an asm boundary.
// Forward: row n of M. Backward: col n.
#define DECLM_F(i) float M_##i; { float _t = tr[n * K2_ + i] * LOG2E_; \
  asm("v_exp_f32 %0, %1\n\ts_nop 1" : "=v"(M_##i) : "v"(_t)); }
#define DECLM_B(i) float M_##i; { float _t = tr[i * K2_ + n] * LOG2E_; \
  asm("v_exp_f32 %0, %1\n\ts_nop 1" : "=v"(M_##i) : "v"(_t)); }

#define ACCQ(Q, i0,i1,i2,i3) \
  _a0 = fmaf(M_##i0, (Q).x, _a0); \
  _a1 = fmaf(M_##i1, (Q).y, _a1); \
  _a2 = fmaf(M_##i2, (Q).z, _a2); \
  _a3 = fmaf(M_##i3, (Q).w, _a3);

#define ACC_ALL \
  ACCQ(_q0 , 0, 1, 2, 3)  ACCQ(_q1 , 4, 5, 6, 7)  ACCQ(_q2 , 8, 9,10,11) \
  ACCQ(_q3 ,12,13,14,15)  ACCQ(_q4 ,16,17,18,19)  ACCQ(_q5 ,20,21,22,23) \
  ACCQ(_q6 ,24,25,26,27)  ACCQ(_q7 ,28,29,30,31)  ACCQ(_q8 ,32,33,34,35) \
  ACCQ(_q9 ,36,37,38,39)  ACCQ(_q10,40,41,42,43)  ACCQ(_q11,44,45,46,47) \
  ACCQ(_qc ,48,49,50,51)

// Forward matvec: read renorm group (48..51, component 50 = .z) first.
#define MATVEC_F(OUTY, RENORMV) \
    const float4* _g4 = (const float4*)sh; \
    float4 _qc  = _g4[12]; \
    float4 _q0  = _g4[0],  _q1  = _g4[1],  _q2  = _g4[2],  _q3  = _g4[3]; \
    float4 _q4  = _g4[4],  _q5  = _g4[5],  _q6  = _g4[6],  _q7  = _g4[7]; \
    float4 _q8  = _g4[8],  _q9  = _g4[9],  _q10 = _g4[10], _q11 = _g4[11]; \
    float RENORMV = _qc.z; (void)RENORMV; \
    float _a0 = 0.0f, _a1 = 0.0f, _a2 = 0.0f, _a3 = 0.0f; \
    ACC_ALL \
    float OUTY = (_a0 + _a1) + (_a2 + _a3);

// Backward matvec: read renorm group (0..3, component 0 = .x) first.
#define MATVEC_B(OUTY, RENORMV) \
    const float4* _g4 = (const float4*)sh; \
    float4 _q0  = _g4[0]; \
    float4 _q1  = _g4[1],  _q2  = _g4[2],  _q3  = _g4[3],  _q4  = _g4[4]; \
    float4 _q5  = _g4[5],  _q6  = _g4[6],  _q7  = _g4[7],  _q8  = _g4[8]; \
    float4 _q9  = _g4[9],  _q10 = _g4[10], _q11 = _g4[11], _qc  = _g4[12]; \
    float RENORMV = _q0.x; (void)RENORMV; \
    float _a0 = 0.0f, _a1 = 0.0f, _a2 = 0.0f, _a3 = 0.0f; \
    ACC_ALL \
    float OUTY = (_a0 + _a1) + (_a2 + _a3);

// ---- forward steps: v' = E_t * (M v); LDS holds v. Renorm comp 50 (>0). ----
#define FSTEP_R(EV, NEWIDX) do {                                \
    float _ne  = emb[(size_t)(NEWIDX) * K2_ + n];               \
    MATVEC_F(_y, _m)                                            \
    float _inv = __builtin_amdgcn_rcpf(_m);                     \
    C += __builtin_amdgcn_logf(_m);                             \
    float _E = __builtin_amdgcn_exp2f((EV) * LOG2E_);           \
    vv = _y * (_inv * _E);                                      \
    sh[lane] = vv;                                              \
    EV = _ne;                                                   \
  } while (0)
#define FSTEP_N(EV, NEWIDX) do {                                \
    float _ne  = emb[(size_t)(NEWIDX) * K2_ + n];               \
    MATVEC_F(_y, _mu)                                           \
    float _E = __builtin_amdgcn_exp2f((EV) * LOG2E_);           \
    vv = _y * _E;                                               \
    sh[lane] = vv;                                              \
    EV = _ne;                                                   \
  } while (0)

// ---- backward steps: LDS holds w = E .* u; step reads w, u' = M^T w, then
//      writes w' = u' * E_next (EV holds the NEXT step's emission). ----
#define BSTEP_R(EV, NEWIDX) do {                                \
    float _ne  = emb[(size_t)(NEWIDX) * K2_ + n];               \
    MATVEC_B(_y, _m)                                            \
    float _inv = __builtin_amdgcn_rcpf(_m);                     \
    C += __builtin_amdgcn_logf(_m);                             \
    vv = _y * _inv;                                             \
    float _E = __builtin_amdgcn_exp2f((EV) * LOG2E_);           \
    sh[lane] = vv * _E;                                         \
    EV = _ne;                                                   \
  } while (0)
#define BSTEP_N(EV, NEWIDX) do {                                \
    float _ne  = emb[(size_t)(NEWIDX) * K2_ + n];               \
    MATVEC_B(_y, _mu)                                           \
    vv = _y;                                                    \
    float _E = __builtin_amdgcn_exp2f((EV) * LOG2E_);           \
    sh[lane] = vv * _E;                                         \
    EV = _ne;                                                   \
  } while (0)

__launch_bounds__(128, 1)
__global__ void crf_fwd_kernel(const float* __restrict__ em,
                               const float* __restrict__ tr,
                               const int*  __restrict__ len,
                               const int*  __restrict__ lab,
                               float* __restrict__ per_b)
{
  const int b    = blockIdx.x;
  const int tid  = threadIdx.x;                      // 128 = 2 waves
  const int wave = tid >> 6;
  const int lane = tid & 63;
  const int n    = (lane < K2_) ? lane : (K2_ - 1);  // lanes 52..63 mirror lane 51
  const int L    = len[b];
  const int h    = L >> 1;                           // forward steps; backward L-h
  const float* emb = em + (size_t)b * (T_ * K2_);

  __shared__ __align__(16) float sV[2][64];   // per-wave state vector (broadcast)
  __shared__ float sCb[1];                    // backward wave's log-offset
  __shared__ float sG[2];                     // per-wave gold partials

  float* sh = sV[wave];
  float vv, C = 0.0f;

  if (wave == 0) {
    // ---------------- forward half: h steps, rows 0..h-1 ----------------
    FORALL52(DECLM_F)
    vv = (lane == 50) ? 1.0f : 0.0f;
    sh[lane] = vv;
    float e0 = emb[0 * K2_ + n];
    float e1 = emb[1 * K2_ + n];
    float e2 = emb[2 * K2_ + n];
    float e3 = emb[3 * K2_ + n];
    int t = 0;
    for (; t + 4 <= h; t += 4) {
      int i4 = imin(t + 4, T_ - 1), i5 = imin(t + 5, T_ - 1);
      int i6 = imin(t + 6, T_ - 1), i7 = imin(t + 7, T_ - 1);
      FSTEP_R(e0, i4);
      FSTEP_N(e1, i5);
      FSTEP_N(e2, i6);
      FSTEP_N(e3, i7);
    }
    int rem = h - t;
    if (rem > 0) FSTEP_R(e0, T_ - 1);
    if (rem > 1) FSTEP_N(e1, T_ - 1);
    if (rem > 2) FSTEP_N(e2, T_ - 1);
  } else {
    // ---------------- backward half: cnt = L-h steps, rows L-1 down to h ----
    FORALL52(DECLM_B)
    vv = __builtin_amdgcn_exp2f(tr[(K2_ - 1) * K2_ + n] * LOG2E_);  // u_0 = s
    int cnt = L - h;
    float e0 = emb[(size_t)(L - 1) * K2_ + n];            // E for step 1 (pre-write)
    float eA = emb[(size_t)imax(L - 2, 0) * K2_ + n];     // next-E for step 1
    float eB = emb[(size_t)imax(L - 3, 0) * K2_ + n];     // next-E for step 2
    float eC = emb[(size_t)imax(L - 4, 0) * K2_ + n];     // next-E for step 3
    float eD = emb[(size_t)imax(L - 5, 0) * K2_ + n];     // next-E for step 4
    sh[lane] = vv * __builtin_amdgcn_exp2f(e0 * LOG2E_);  // w_0 = E_{L-1} .* u_0
    int s = 0;
    for (; s + 4 <= cnt; s += 4) {
      int j4 = imax(L - 6 - s, 0), j5 = imax(L - 7 - s, 0);
      int j6 = imax(L - 8 - s, 0), j7 = imax(L - 9 - s, 0);
      BSTEP_R(eA, j4);
      BSTEP_N(eB, j5);
      BSTEP_N(eC, j6);
      BSTEP_N(eD, j7);
    }
    int rem = cnt - s;
    if (rem > 0) BSTEP_R(eA, 0);
    if (rem > 1) BSTEP_N(eB, 0);
    if (rem > 2) BSTEP_N(eC, 0);

    sh[lane] = vv;              // publish final u (overwrites w buffer)
    if (lane == 0) sCb[0] = C;
  }

  // ---- gold score (both waves, stride 128) ----
  float gold = 0.0f;
  const int* labb = lab + b * T_;
  for (int tt = tid; tt < L; tt += 128) {
    int l1 = labb[tt];
    int l0 = (tt == 0) ? 50 : labb[tt - 1];
    gold += emb[(size_t)tt * K2_ + l1] + tr[l1 * K2_ + l0];
  }
  if (tid == 0) gold += tr[(K2_ - 1) * K2_ + labb[L - 1]];  // STOP <- last label
#pragma unroll
  for (int off = 32; off >= 1; off >>= 1)
    gold += __shfl_xor(gold, off, 64);
  if (lane == 0) sG[wave] = gold;

  __syncthreads();

  if (wave == 0) {
    // dot(u, v) + combine log-offsets
    float x = (lane < K2_) ? vv * sV[1][lane] : 0.0f;
#pragma unroll
    for (int off = 32; off >= 1; off >>= 1)
      x += __shfl_xor(x, off, 64);
    float fwd = (C + sCb[0] + __builtin_amdgcn_logf(x)) * LN2_;
    if (lane == 0) per_b[b] = fwd - (sG[0] + sG[1]);
  }
}

__global__ void reduce_mean_kernel(const float* __restrict__ per_b,
                                   float* __restrict__ out)
{
  const int tid = threadIdx.x;  // 256
  float v = per_b[tid];
#pragma unroll
  for (int off = 32; off >= 1; off >>= 1) v += __shfl_xor(v, off, 64);
  __shared__ float s[4];
  if ((tid & 63) == 0) s[tid >> 6] = v;
  __syncthreads();
  if (tid == 0) out[0] = ((s[0] + s[1]) + (s[2] + s[3])) * (1.0f / (float)B_);
}

extern "C" void kernel_launch(void* const* d_in, const int* in_sizes, int n_in,
                              void* d_out, int out_size, void* d_ws, size_t ws_size,
                              hipStream_t stream) {
  const float* em  = (const float*)d_in[0];   // [B,T,K2] f32
  const float* tr  = (const float*)d_in[1];   // [K2,K2]  f32
  const int*   len = (const int*)d_in[2];     // [B] i32
  const int*   lab = (const int*)d_in[3];     // [B,T] i32
  float* out = (float*)d_out;
  float* ws  = (float*)d_ws;                  // 256 floats of per-batch scores

  crf_fwd_kernel<<<B_, 128, 0, stream>>>(em, tr, len, lab, ws);
  reduce_mean_kernel<<<1, 256, 0, stream>>>(ws, out);
}